// Round 13
// baseline (209.250 us; speedup 1.0000x reference)
//
#include <hip/hip_runtime.h>
#include <stdint.h>

// Shapes (fixed by problem)
#define DIMD 1024
#define HEADS 16
#define HD 64
#define SEQ 2048
#define NBATCH 2
#define TOKENS 4096
#define BH 32

typedef __bf16 bf16x8 __attribute__((ext_vector_type(8)));
typedef float f32x4 __attribute__((ext_vector_type(4)));

#if __has_builtin(__builtin_amdgcn_exp2f)
#define EXP2(x) __builtin_amdgcn_exp2f(x)
#else
#define EXP2(x) exp2f(x)
#endif

#if __has_builtin(__builtin_amdgcn_cvt_pk_bf16_f32)
typedef __bf16 bf16x2 __attribute__((ext_vector_type(2)));
__device__ inline unsigned int pack2(float a, float b) {
    bf16x2 r = __builtin_amdgcn_cvt_pk_bf16_f32(a, b);
    return __builtin_bit_cast(unsigned int, r);
}
__device__ inline unsigned short f2bf(float f) {
    bf16x2 r = __builtin_amdgcn_cvt_pk_bf16_f32(f, f);
    return (unsigned short)(__builtin_bit_cast(unsigned int, r) & 0xffffu);
}
#else
__device__ inline unsigned short f2bf(float f) {
    unsigned int u = __builtin_bit_cast(unsigned int, f) + 0x8000u;
    return (unsigned short)(u >> 16);
}
__device__ inline unsigned int pack2(float a, float b) {
    unsigned int ua = __builtin_bit_cast(unsigned int, a) + 0x8000u;
    unsigned int ub = __builtin_bit_cast(unsigned int, b) + 0x8000u;
    return (ua >> 16) | (ub & 0xffff0000u);
}
#endif

// async global->LDS, 16B per lane, dest = wave-uniform base + lane*16
__device__ inline void gl_lds16(const void* g, void* l) {
    __builtin_amdgcn_global_load_lds(
        (const __attribute__((address_space(1))) unsigned int*)g,
        (__attribute__((address_space(3))) unsigned int*)l, 16, 0, 0);
}

// log2(e) * DIM^-0.5  (folded into Q at GEMM1 epilogue)
#define CEQ 0.0450842200277801f

// ------------- prep: cast x -> bf16 AND transpose-cast both weights ----
__global__ __launch_bounds__(256) void prep(const float* __restrict__ x,
                                            const float* __restrict__ wqkv,
                                            const float* __restrict__ wout,
                                            short* __restrict__ xb,
                                            short* __restrict__ wqkvt,
                                            short* __restrict__ woutt) {
    __shared__ short T[64 * 68];
    int bid = blockIdx.x, t = threadIdx.x;
    if (bid < 2048) {
        int g = bid * 256 + t;
        const float4* p = (const float4*)x + (size_t)g * 2;
        float4 a = p[0], b = p[1];
        uint4 o;
        o.x = pack2(a.x, a.y); o.y = pack2(a.z, a.w);
        o.z = pack2(b.x, b.y); o.w = pack2(b.z, b.w);
        ((uint4*)xb)[g] = o;
        return;
    }
    const float* w; short* wt; int N, n0, k0;
    if (bid < 2816) { int l = bid - 2048; w = wqkv; wt = wqkvt; N = 3072; n0 = (l % 48) * 64; k0 = (l / 48) * 64; }
    else            { int l = bid - 2816; w = wout; wt = woutt; N = 1024; n0 = (l % 16) * 64; k0 = (l / 16) * 64; }
    for (int e = 0; e < 4; e++) {
        int lin = t + e * 256;
        int r = lin >> 4, c = (lin & 15) * 4;
        float4 v = *(const float4*)(w + (size_t)(k0 + r) * N + n0 + c);
        *(uint2*)&T[r * 68 + c] = make_uint2(pack2(v.x, v.y), pack2(v.z, v.w));
    }
    __syncthreads();
    for (int e = 0; e < 4; e++) {
        int lin = t + e * 256;
        int nr = lin >> 4, kc = (lin & 15) * 4;
        unsigned short a0 = (unsigned short)T[(kc + 0) * 68 + nr];
        unsigned short a1 = (unsigned short)T[(kc + 1) * 68 + nr];
        unsigned short a2 = (unsigned short)T[(kc + 2) * 68 + nr];
        unsigned short a3 = (unsigned short)T[(kc + 3) * 68 + nr];
        *(uint2*)(wt + (size_t)(n0 + nr) * 1024 + k0 + kc) =
            make_uint2((unsigned int)a0 | ((unsigned int)a1 << 16),
                       (unsigned int)a2 | ((unsigned int)a3 << 16));
    }
}

// ---------------- GEMM1 v3 (r12-proven): 128x64 tiles, 6 blocks/CU -----
__global__ __launch_bounds__(256, 6) void gemm_qkv(const short* __restrict__ A,
                                                   const short* __restrict__ Bt,
                                                   short* __restrict__ Qb,
                                                   short* __restrict__ Kb,
                                                   short* __restrict__ Vtb) {
    __shared__ short As[2][128 * 32];
    __shared__ short Bs[2][64 * 32];
    int gid = blockIdx.x;
    int sg = gid >> 4, wi = gid & 15;
    int mt = (sg / 12) * 4 + (wi >> 2);
    int nt = (sg % 12) * 4 + (wi & 3);
    int t = threadIdx.x, w = t >> 6, lane = t & 63, c = lane & 15, q = lane >> 4;
    int mw = (w & 1) * 64, nw = (w >> 1) * 32;
    int h3 = lane >> 3, s3 = lane & 7, cp = s3 ^ h3;
    int rowin = 2 * h3 + (cp >> 2), koff = (cp & 3) * 16;
    const char* Ag0 = (const char*)A + (size_t)(mt * 128 + w * 32 + rowin) * 2048 + koff;
    const char* Ag1 = Ag0 + (size_t)16 * 2048;
    const char* Bg0 = (const char*)Bt + (size_t)(nt * 64 + w * 16 + rowin) * 2048 + koff;
    int cb = (c >> 1) * 128 + ((((c & 1) * 4 + q) ^ ((c >> 1) & 7)) * 16);
    f32x4 acc[4][2] = {};
    gl_lds16(Ag0, (char*)As[0] + w * 2048);
    gl_lds16(Ag1, (char*)As[0] + w * 2048 + 1024);
    gl_lds16(Bg0, (char*)Bs[0] + w * 1024);
    __syncthreads();
    for (int kt = 0; kt < 32; kt++) {
        int bu = kt & 1;
        if (kt < 31) {
            gl_lds16(Ag0 + (kt + 1) * 64, (char*)As[bu ^ 1] + w * 2048);
            gl_lds16(Ag1 + (kt + 1) * 64, (char*)As[bu ^ 1] + w * 2048 + 1024);
            gl_lds16(Bg0 + (kt + 1) * 64, (char*)Bs[bu ^ 1] + w * 1024);
        }
        bf16x8 af[4], bfr[2];
        for (int mf = 0; mf < 4; mf++)
            af[mf] = *(bf16x8*)((char*)As[bu] + (mw + mf * 16) * 64 + cb);
        for (int nf = 0; nf < 2; nf++)
            bfr[nf] = *(bf16x8*)((char*)Bs[bu] + (nw + nf * 16) * 64 + cb);
        for (int mf = 0; mf < 4; mf++)
            for (int nf = 0; nf < 2; nf++)
                acc[mf][nf] = __builtin_amdgcn_mfma_f32_16x16x32_bf16(
                    af[mf], bfr[nf], acc[mf][nf], 0, 0, 0);
        __syncthreads();
    }
    for (int nf = 0; nf < 2; nf++) {
        int col = nt * 64 + nw + nf * 16 + c;
        int sel = col >> 10, cw = col & 1023, h = cw >> 6, d = cw & 63;
        float sc = (sel == 0) ? CEQ : 1.0f;
        for (int mf = 0; mf < 4; mf++) {
            int m0 = mt * 128 + mw + mf * 16 + q * 4;
            int b = m0 >> 11, nn = m0 & 2047;
            int bh = b * 16 + h;
            if (sel == 2) {
                *(uint2*)(Vtb + ((size_t)bh * 64 + d) * 2048 + nn) =
                    make_uint2(pack2(acc[mf][nf][0], acc[mf][nf][1]),
                               pack2(acc[mf][nf][2], acc[mf][nf][3]));
            } else {
                short* dst = (sel ? Kb : Qb) + ((size_t)bh * 2048 + nn) * 64 + d;
                dst[0]   = (short)f2bf(acc[mf][nf][0] * sc);
                dst[64]  = (short)f2bf(acc[mf][nf][1] * sc);
                dst[128] = (short)f2bf(acc[mf][nf][2] * sc);
                dst[192] = (short)f2bf(acc[mf][nf][3] * sc);
            }
        }
    }
}

// ---------------- flash attention v7: r12 j-split + l via ones-MFMA ----
// l computed by 4 extra MFMAs/jtile (A=ones) on the 26%-busy MFMA pipe;
// removes ~16 VALU adds + 4 shuffles per wave-jtile (r11-validated math:
// every C-row of ones*P^T equals l[i=c], so each lane holds its own l).
__global__ __launch_bounds__(512, 4) void flash_attn(const short* __restrict__ Qb,
                                                     const short* __restrict__ Kb,
                                                     const short* __restrict__ Vtb,
                                                     short* __restrict__ Ob) {
    __shared__ __align__(16) char smem[70144];
    char* ktp = smem;
    char* vtp = smem + 16384;
    char* plp = smem + 32768;
    float* lxp = (float*)(smem + 69632);
    int bh = blockIdx.x, qt = blockIdx.y;
    int t = threadIdx.x, w = t >> 6, lane = t & 63, c = lane & 15, q = lane >> 4;
    int wi = w & 3, hf = w >> 2;
    const short* Qh = Qb + (size_t)bh * SEQ * HD;
    short* plw = (short*)(plp + w * 4608);
    bf16x8 bq[2][2];
    for (int i2 = 0; i2 < 2; i2++)
        for (int ks = 0; ks < 2; ks++)
            bq[i2][ks] = *(const bf16x8*)(Qh + (size_t)(qt * 128 + wi * 32 + i2 * 16 + c) * 64 + ks * 32 + q * 8);
    int rl = lane >> 3, sl = lane & 7, ch = sl ^ rl;
    const char* Ksrc = (const char*)(Kb + (size_t)bh * SEQ * HD)
                       + (size_t)(hf * 1024 + wi * 16 + rl) * 128 + ch * 16;
    const char* Vsrc = (const char*)(Vtb + (size_t)bh * HD * SEQ)
                       + (size_t)(wi * 16 + rl) * 4096 + hf * 2048 + ch * 16;
    char* kb = ktp + hf * 8192 + wi * 2048;
    char* vb = vtp + hf * 8192 + wi * 2048;
    char* kth = ktp + hf * 8192;
    char* vth = vtp + hf * 8192;
    int sw0 = ((0 * 4 + q) ^ (c & 7)) * 16;
    int sw1 = ((1 * 4 + q) ^ (c & 7)) * 16;
    bf16x8 ones;
    {
        unsigned short ob = 0x3F80;
        __bf16 ov = __builtin_bit_cast(__bf16, ob);
        for (int e = 0; e < 8; e++) ones[e] = ov;
    }
    f32x4 lacc[2] = {};
    f32x4 of[4][2] = {};
    for (int e = 0; e < 2; e++) {
        gl_lds16(Ksrc + e * 1024, kb + e * 1024);
        gl_lds16(Vsrc + (size_t)e * 32768, vb + e * 1024);
    }
    __syncthreads();
    for (int jt = 0; jt < 16; jt++) {
        f32x4 st[4][2] = {};
        for (int jf = 0; jf < 4; jf++) {
            bf16x8 ka0 = *(bf16x8*)(kth + (jf * 16 + c) * 128 + sw0);
            bf16x8 ka1 = *(bf16x8*)(kth + (jf * 16 + c) * 128 + sw1);
            for (int i2 = 0; i2 < 2; i2++)
                st[jf][i2] = __builtin_amdgcn_mfma_f32_16x16x32_bf16(
                    ka0, bq[i2][0], st[jf][i2], 0, 0, 0);
            for (int i2 = 0; i2 < 2; i2++)
                st[jf][i2] = __builtin_amdgcn_mfma_f32_16x16x32_bf16(
                    ka1, bq[i2][1], st[jf][i2], 0, 0, 0);
        }
        for (int i2 = 0; i2 < 2; i2++) {
            for (int jf = 0; jf < 4; jf++) {
                float p0 = EXP2(st[jf][i2][0]);
                float p1 = EXP2(st[jf][i2][1]);
                float p2 = EXP2(st[jf][i2][2]);
                float p3 = EXP2(st[jf][i2][3]);
                *(uint2*)(plw + (i2 * 16 + c) * 72 + jf * 16 + q * 4) =
                    make_uint2(pack2(p0, p1), pack2(p2, p3));
            }
        }
        for (int ks = 0; ks < 2; ks++) {
            int swk = ks ? sw1 : sw0;
            bf16x8 pb[2];
            for (int i2 = 0; i2 < 2; i2++)
                pb[i2] = *(bf16x8*)((char*)plw + (i2 * 16 + c) * 144 + ks * 64 + q * 16);
            for (int mf = 0; mf < 4; mf++) {
                bf16x8 va = *(bf16x8*)(vth + (mf * 16 + c) * 128 + swk);
                for (int i2 = 0; i2 < 2; i2++)
                    of[mf][i2] = __builtin_amdgcn_mfma_f32_16x16x32_bf16(
                        va, pb[i2], of[mf][i2], 0, 0, 0);
            }
            for (int i2 = 0; i2 < 2; i2++)
                lacc[i2] = __builtin_amdgcn_mfma_f32_16x16x32_bf16(
                    ones, pb[i2], lacc[i2], 0, 0, 0);
        }
        __syncthreads();
        if (jt < 15) {
            for (int e = 0; e < 2; e++) {
                gl_lds16(Ksrc + (size_t)(jt + 1) * 8192 + e * 1024, kb + e * 1024);
                gl_lds16(Vsrc + (size_t)(jt + 1) * 128 + (size_t)e * 32768, vb + e * 1024);
            }
        }
        __syncthreads();
    }
    float l0 = lacc[0][0], l1 = lacc[1][0];        // every lane holds l for its c
    if (w >= 4) {
        float* ex = (float*)smem + (w - 4) * 2048;
        for (int mf = 0; mf < 4; mf++)
            for (int i2 = 0; i2 < 2; i2++)
                *(f32x4*)(ex + (mf * 2 + i2) * 256 + lane * 4) = of[mf][i2];
        if (lane < 16) { lxp[(w - 4) * 32 + lane] = l0; lxp[(w - 4) * 32 + 16 + lane] = l1; }
    }
    __syncthreads();
    if (w < 4) {
        float* ex = (float*)smem + w * 2048;
        for (int mf = 0; mf < 4; mf++)
            for (int i2 = 0; i2 < 2; i2++)
                of[mf][i2] += *(f32x4*)(ex + (mf * 2 + i2) * 256 + lane * 4);
        l0 += lxp[w * 32 + c];
        l1 += lxp[w * 32 + 16 + c];
        float inv0 = 1.f / l0, inv1 = 1.f / l1;
        for (int mf = 0; mf < 4; mf++) {
            *(uint2*)(plw + (0 * 16 + c) * 72 + mf * 16 + q * 4) =
                make_uint2(pack2(of[mf][0][0] * inv0, of[mf][0][1] * inv0),
                           pack2(of[mf][0][2] * inv0, of[mf][0][3] * inv0));
            *(uint2*)(plw + (1 * 16 + c) * 72 + mf * 16 + q * 4) =
                make_uint2(pack2(of[mf][1][0] * inv1, of[mf][1][1] * inv1),
                           pack2(of[mf][1][2] * inv1, of[mf][1][3] * inv1));
        }
        int b2 = bh >> 4, h = bh & 15;
        for (int e = 0; e < 4; e++) {
            int chn = e * 64 + lane;
            int i = chn >> 3, db = (chn & 7) * 16;
            float4 v = *(float4*)((char*)plw + i * 144 + db);
            int token = b2 * 2048 + qt * 128 + w * 32 + i;
            *(float4*)((char*)Ob + (size_t)token * 2048 + h * 128 + db) = v;
        }
    }
}

// ---------------- GEMM2 v2: split-K=2, atomicAdd into zeroed out -------
// 1024 blocks (vs 512): each handles half the K range (16 iters). Fixes
// the 2-blocks/CU TLP starvation (same mechanism as r10 flash / r12 qkv).
// d_out is zeroed via hipMemsetAsync; split hk=0 contributes the bias.
__global__ __launch_bounds__(256) void gemm_out(const short* __restrict__ A,
                                                const short* __restrict__ Bt,
                                                const float* __restrict__ bias,
                                                float* __restrict__ out) {
    __shared__ short As[2][128 * 32];
    __shared__ short Bs[2][64 * 32];
    int gid = blockIdx.x;
    int hk = gid >> 9;                             // K-split half
    int sp = gid & 511;
    int sg = sp >> 4, wi = sp & 15;
    int mt = (sg / 4) * 4 + (wi >> 2);
    int nt = (sg % 4) * 4 + (wi & 3);
    int t = threadIdx.x, w = t >> 6, lane = t & 63, c = lane & 15, q = lane >> 4;
    int mw = (w & 1) * 64, nw = (w >> 1) * 32;
    int h3 = lane >> 3, s3 = lane & 7, cp = s3 ^ h3;
    int rowin = 2 * h3 + (cp >> 2), koff = (cp & 3) * 16;
    const char* Ag0 = (const char*)A + (size_t)(mt * 128 + w * 32 + rowin) * 2048 + hk * 1024 + koff;
    const char* Ag1 = Ag0 + (size_t)16 * 2048;
    const char* Bg0 = (const char*)Bt + (size_t)(nt * 64 + w * 16 + rowin) * 2048 + hk * 1024 + koff;
    int cb = (c >> 1) * 128 + ((((c & 1) * 4 + q) ^ ((c >> 1) & 7)) * 16);
    f32x4 acc[4][2] = {};
    gl_lds16(Ag0, (char*)As[0] + w * 2048);
    gl_lds16(Ag1, (char*)As[0] + w * 2048 + 1024);
    gl_lds16(Bg0, (char*)Bs[0] + w * 1024);
    __syncthreads();
    for (int kt = 0; kt < 16; kt++) {
        int bu = kt & 1;
        if (kt < 15) {
            gl_lds16(Ag0 + (kt + 1) * 64, (char*)As[bu ^ 1] + w * 2048);
            gl_lds16(Ag1 + (kt + 1) * 64, (char*)As[bu ^ 1] + w * 2048 + 1024);
            gl_lds16(Bg0 + (kt + 1) * 64, (char*)Bs[bu ^ 1] + w * 1024);
        }
        bf16x8 af[4], bfr[2];
        for (int mf = 0; mf < 4; mf++)
            af[mf] = *(bf16x8*)((char*)As[bu] + (mw + mf * 16) * 64 + cb);
        for (int nf = 0; nf < 2; nf++)
            bfr[nf] = *(bf16x8*)((char*)Bs[bu] + (nw + nf * 16) * 64 + cb);
        for (int mf = 0; mf < 4; mf++)
            for (int nf = 0; nf < 2; nf++)
                acc[mf][nf] = __builtin_amdgcn_mfma_f32_16x16x32_bf16(
                    af[mf], bfr[nf], acc[mf][nf], 0, 0, 0);
        __syncthreads();
    }
    for (int nf = 0; nf < 2; nf++) {
        int col = nt * 64 + nw + nf * 16 + c;
        float bv = (hk == 0) ? bias[col] : 0.0f;
        for (int mf = 0; mf < 4; mf++) {
            int m0 = mt * 128 + mw + mf * 16 + q * 4;
            float* dst = out + (size_t)m0 * 1024 + col;
            atomicAdd(&dst[0],    acc[mf][nf][0] + bv);
            atomicAdd(&dst[1024], acc[mf][nf][1] + bv);
            atomicAdd(&dst[2048], acc[mf][nf][2] + bv);
            atomicAdd(&dst[3072], acc[mf][nf][3] + bv);
        }
    }
}

extern "C" void kernel_launch(void* const* d_in, const int* in_sizes, int n_in,
                              void* d_out, int out_size, void* d_ws, size_t ws_size,
                              hipStream_t stream) {
    (void)in_sizes; (void)n_in; (void)out_size; (void)ws_size;
    const float* x     = (const float*)d_in[0];
    const float* w_qkv = (const float*)d_in[1];
    const float* w_out = (const float*)d_in[2];
    const float* b_out = (const float*)d_in[3];
    float* out = (float*)d_out;

    short* xb    = (short*)d_ws;
    short* wqkvt = xb    + 4096 * 1024;
    short* woutt = wqkvt + 3072 * 1024;
    short* Qb    = woutt + 1024 * 1024;
    short* Kb    = Qb    + BH * SEQ * HD;
    short* Vtb   = Kb    + BH * SEQ * HD;
    short* Ob    = Vtb   + BH * HD * SEQ;

    hipLaunchKernelGGL(prep, dim3(3072), dim3(256), 0, stream, x, w_qkv, w_out, xb, wqkvt, woutt);
    hipLaunchKernelGGL(gemm_qkv, dim3(1536), dim3(256), 0, stream, xb, wqkvt, Qb, Kb, Vtb);
    hipLaunchKernelGGL(flash_attn, dim3(32, 16), dim3(512), 0, stream, Qb, Kb, Vtb, Ob);
    hipMemsetAsync(out, 0, (size_t)TOKENS * DIMD * sizeof(float), stream);
    hipLaunchKernelGGL(gemm_out, dim3(1024), dim3(256), 0, stream, Ob, woutt, b_out, out);
}

// Round 14
// 187.652 us; speedup vs baseline: 1.1151x; 1.1151x over previous
//
#include <hip/hip_runtime.h>
#include <stdint.h>

// Shapes (fixed by problem)
#define DIMD 1024
#define HEADS 16
#define HD 64
#define SEQ 2048
#define NBATCH 2
#define TOKENS 4096
#define BH 32

typedef __bf16 bf16x8 __attribute__((ext_vector_type(8)));
typedef float f32x4 __attribute__((ext_vector_type(4)));

#if __has_builtin(__builtin_amdgcn_exp2f)
#define EXP2(x) __builtin_amdgcn_exp2f(x)
#else
#define EXP2(x) exp2f(x)
#endif

#if __has_builtin(__builtin_amdgcn_cvt_pk_bf16_f32)
typedef __bf16 bf16x2 __attribute__((ext_vector_type(2)));
__device__ inline unsigned int pack2(float a, float b) {
    bf16x2 r = __builtin_amdgcn_cvt_pk_bf16_f32(a, b);
    return __builtin_bit_cast(unsigned int, r);
}
__device__ inline unsigned short f2bf(float f) {
    bf16x2 r = __builtin_amdgcn_cvt_pk_bf16_f32(f, f);
    return (unsigned short)(__builtin_bit_cast(unsigned int, r) & 0xffffu);
}
#else
__device__ inline unsigned short f2bf(float f) {
    unsigned int u = __builtin_bit_cast(unsigned int, f) + 0x8000u;
    return (unsigned short)(u >> 16);
}
__device__ inline unsigned int pack2(float a, float b) {
    unsigned int ua = __builtin_bit_cast(unsigned int, a) + 0x8000u;
    unsigned int ub = __builtin_bit_cast(unsigned int, b) + 0x8000u;
    return (ua >> 16) | (ub & 0xffff0000u);
}
#endif

// async global->LDS, 16B per lane, dest = wave-uniform base + lane*16
__device__ inline void gl_lds16(const void* g, void* l) {
    __builtin_amdgcn_global_load_lds(
        (const __attribute__((address_space(1))) unsigned int*)g,
        (__attribute__((address_space(3))) unsigned int*)l, 16, 0, 0);
}

// log2(e) * DIM^-0.5  (folded into Q at GEMM1 epilogue)
#define CEQ 0.0450842200277801f

// ------------- prep: cast x -> bf16 AND transpose-cast both weights ----
__global__ __launch_bounds__(256) void prep(const float* __restrict__ x,
                                            const float* __restrict__ wqkv,
                                            const float* __restrict__ wout,
                                            short* __restrict__ xb,
                                            short* __restrict__ wqkvt,
                                            short* __restrict__ woutt) {
    __shared__ short T[64 * 68];
    int bid = blockIdx.x, t = threadIdx.x;
    if (bid < 2048) {
        int g = bid * 256 + t;
        const float4* p = (const float4*)x + (size_t)g * 2;
        float4 a = p[0], b = p[1];
        uint4 o;
        o.x = pack2(a.x, a.y); o.y = pack2(a.z, a.w);
        o.z = pack2(b.x, b.y); o.w = pack2(b.z, b.w);
        ((uint4*)xb)[g] = o;
        return;
    }
    const float* w; short* wt; int N, n0, k0;
    if (bid < 2816) { int l = bid - 2048; w = wqkv; wt = wqkvt; N = 3072; n0 = (l % 48) * 64; k0 = (l / 48) * 64; }
    else            { int l = bid - 2816; w = wout; wt = woutt; N = 1024; n0 = (l % 16) * 64; k0 = (l / 16) * 64; }
    for (int e = 0; e < 4; e++) {
        int lin = t + e * 256;
        int r = lin >> 4, c = (lin & 15) * 4;
        float4 v = *(const float4*)(w + (size_t)(k0 + r) * N + n0 + c);
        *(uint2*)&T[r * 68 + c] = make_uint2(pack2(v.x, v.y), pack2(v.z, v.w));
    }
    __syncthreads();
    for (int e = 0; e < 4; e++) {
        int lin = t + e * 256;
        int nr = lin >> 4, kc = (lin & 15) * 4;
        unsigned short a0 = (unsigned short)T[(kc + 0) * 68 + nr];
        unsigned short a1 = (unsigned short)T[(kc + 1) * 68 + nr];
        unsigned short a2 = (unsigned short)T[(kc + 2) * 68 + nr];
        unsigned short a3 = (unsigned short)T[(kc + 3) * 68 + nr];
        *(uint2*)(wt + (size_t)(n0 + nr) * 1024 + k0 + kc) =
            make_uint2((unsigned int)a0 | ((unsigned int)a1 << 16),
                       (unsigned int)a2 | ((unsigned int)a3 << 16));
    }
}

// ---------------- GEMM1 v3 (r12-proven): 128x64 tiles, 6 blocks/CU -----
__global__ __launch_bounds__(256, 6) void gemm_qkv(const short* __restrict__ A,
                                                   const short* __restrict__ Bt,
                                                   short* __restrict__ Qb,
                                                   short* __restrict__ Kb,
                                                   short* __restrict__ Vtb) {
    __shared__ short As[2][128 * 32];
    __shared__ short Bs[2][64 * 32];
    int gid = blockIdx.x;
    int sg = gid >> 4, wi = gid & 15;
    int mt = (sg / 12) * 4 + (wi >> 2);
    int nt = (sg % 12) * 4 + (wi & 3);
    int t = threadIdx.x, w = t >> 6, lane = t & 63, c = lane & 15, q = lane >> 4;
    int mw = (w & 1) * 64, nw = (w >> 1) * 32;
    int h3 = lane >> 3, s3 = lane & 7, cp = s3 ^ h3;
    int rowin = 2 * h3 + (cp >> 2), koff = (cp & 3) * 16;
    const char* Ag0 = (const char*)A + (size_t)(mt * 128 + w * 32 + rowin) * 2048 + koff;
    const char* Ag1 = Ag0 + (size_t)16 * 2048;
    const char* Bg0 = (const char*)Bt + (size_t)(nt * 64 + w * 16 + rowin) * 2048 + koff;
    int cb = (c >> 1) * 128 + ((((c & 1) * 4 + q) ^ ((c >> 1) & 7)) * 16);
    f32x4 acc[4][2] = {};
    gl_lds16(Ag0, (char*)As[0] + w * 2048);
    gl_lds16(Ag1, (char*)As[0] + w * 2048 + 1024);
    gl_lds16(Bg0, (char*)Bs[0] + w * 1024);
    __syncthreads();
    for (int kt = 0; kt < 32; kt++) {
        int bu = kt & 1;
        if (kt < 31) {
            gl_lds16(Ag0 + (kt + 1) * 64, (char*)As[bu ^ 1] + w * 2048);
            gl_lds16(Ag1 + (kt + 1) * 64, (char*)As[bu ^ 1] + w * 2048 + 1024);
            gl_lds16(Bg0 + (kt + 1) * 64, (char*)Bs[bu ^ 1] + w * 1024);
        }
        bf16x8 af[4], bfr[2];
        for (int mf = 0; mf < 4; mf++)
            af[mf] = *(bf16x8*)((char*)As[bu] + (mw + mf * 16) * 64 + cb);
        for (int nf = 0; nf < 2; nf++)
            bfr[nf] = *(bf16x8*)((char*)Bs[bu] + (nw + nf * 16) * 64 + cb);
        for (int mf = 0; mf < 4; mf++)
            for (int nf = 0; nf < 2; nf++)
                acc[mf][nf] = __builtin_amdgcn_mfma_f32_16x16x32_bf16(
                    af[mf], bfr[nf], acc[mf][nf], 0, 0, 0);
        __syncthreads();
    }
    for (int nf = 0; nf < 2; nf++) {
        int col = nt * 64 + nw + nf * 16 + c;
        int sel = col >> 10, cw = col & 1023, h = cw >> 6, d = cw & 63;
        float sc = (sel == 0) ? CEQ : 1.0f;
        for (int mf = 0; mf < 4; mf++) {
            int m0 = mt * 128 + mw + mf * 16 + q * 4;
            int b = m0 >> 11, nn = m0 & 2047;
            int bh = b * 16 + h;
            if (sel == 2) {
                *(uint2*)(Vtb + ((size_t)bh * 64 + d) * 2048 + nn) =
                    make_uint2(pack2(acc[mf][nf][0], acc[mf][nf][1]),
                               pack2(acc[mf][nf][2], acc[mf][nf][3]));
            } else {
                short* dst = (sel ? Kb : Qb) + ((size_t)bh * 2048 + nn) * 64 + d;
                dst[0]   = (short)f2bf(acc[mf][nf][0] * sc);
                dst[64]  = (short)f2bf(acc[mf][nf][1] * sc);
                dst[128] = (short)f2bf(acc[mf][nf][2] * sc);
                dst[192] = (short)f2bf(acc[mf][nf][3] * sc);
            }
        }
    }
}

// ---------------- flash attention v7 (r13-proven): l via ones-MFMA -----
__global__ __launch_bounds__(512, 4) void flash_attn(const short* __restrict__ Qb,
                                                     const short* __restrict__ Kb,
                                                     const short* __restrict__ Vtb,
                                                     short* __restrict__ Ob) {
    __shared__ __align__(16) char smem[70144];
    char* ktp = smem;
    char* vtp = smem + 16384;
    char* plp = smem + 32768;
    float* lxp = (float*)(smem + 69632);
    int bh = blockIdx.x, qt = blockIdx.y;
    int t = threadIdx.x, w = t >> 6, lane = t & 63, c = lane & 15, q = lane >> 4;
    int wi = w & 3, hf = w >> 2;
    const short* Qh = Qb + (size_t)bh * SEQ * HD;
    short* plw = (short*)(plp + w * 4608);
    bf16x8 bq[2][2];
    for (int i2 = 0; i2 < 2; i2++)
        for (int ks = 0; ks < 2; ks++)
            bq[i2][ks] = *(const bf16x8*)(Qh + (size_t)(qt * 128 + wi * 32 + i2 * 16 + c) * 64 + ks * 32 + q * 8);
    int rl = lane >> 3, sl = lane & 7, ch = sl ^ rl;
    const char* Ksrc = (const char*)(Kb + (size_t)bh * SEQ * HD)
                       + (size_t)(hf * 1024 + wi * 16 + rl) * 128 + ch * 16;
    const char* Vsrc = (const char*)(Vtb + (size_t)bh * HD * SEQ)
                       + (size_t)(wi * 16 + rl) * 4096 + hf * 2048 + ch * 16;
    char* kb = ktp + hf * 8192 + wi * 2048;
    char* vb = vtp + hf * 8192 + wi * 2048;
    char* kth = ktp + hf * 8192;
    char* vth = vtp + hf * 8192;
    int sw0 = ((0 * 4 + q) ^ (c & 7)) * 16;
    int sw1 = ((1 * 4 + q) ^ (c & 7)) * 16;
    bf16x8 ones;
    {
        unsigned short ob = 0x3F80;
        __bf16 ov = __builtin_bit_cast(__bf16, ob);
        for (int e = 0; e < 8; e++) ones[e] = ov;
    }
    f32x4 lacc[2] = {};
    f32x4 of[4][2] = {};
    for (int e = 0; e < 2; e++) {
        gl_lds16(Ksrc + e * 1024, kb + e * 1024);
        gl_lds16(Vsrc + (size_t)e * 32768, vb + e * 1024);
    }
    __syncthreads();
    for (int jt = 0; jt < 16; jt++) {
        f32x4 st[4][2] = {};
        for (int jf = 0; jf < 4; jf++) {
            bf16x8 ka0 = *(bf16x8*)(kth + (jf * 16 + c) * 128 + sw0);
            bf16x8 ka1 = *(bf16x8*)(kth + (jf * 16 + c) * 128 + sw1);
            for (int i2 = 0; i2 < 2; i2++)
                st[jf][i2] = __builtin_amdgcn_mfma_f32_16x16x32_bf16(
                    ka0, bq[i2][0], st[jf][i2], 0, 0, 0);
            for (int i2 = 0; i2 < 2; i2++)
                st[jf][i2] = __builtin_amdgcn_mfma_f32_16x16x32_bf16(
                    ka1, bq[i2][1], st[jf][i2], 0, 0, 0);
        }
        for (int i2 = 0; i2 < 2; i2++) {
            for (int jf = 0; jf < 4; jf++) {
                float p0 = EXP2(st[jf][i2][0]);
                float p1 = EXP2(st[jf][i2][1]);
                float p2 = EXP2(st[jf][i2][2]);
                float p3 = EXP2(st[jf][i2][3]);
                *(uint2*)(plw + (i2 * 16 + c) * 72 + jf * 16 + q * 4) =
                    make_uint2(pack2(p0, p1), pack2(p2, p3));
            }
        }
        for (int ks = 0; ks < 2; ks++) {
            int swk = ks ? sw1 : sw0;
            bf16x8 pb[2];
            for (int i2 = 0; i2 < 2; i2++)
                pb[i2] = *(bf16x8*)((char*)plw + (i2 * 16 + c) * 144 + ks * 64 + q * 16);
            for (int mf = 0; mf < 4; mf++) {
                bf16x8 va = *(bf16x8*)(vth + (mf * 16 + c) * 128 + swk);
                for (int i2 = 0; i2 < 2; i2++)
                    of[mf][i2] = __builtin_amdgcn_mfma_f32_16x16x32_bf16(
                        va, pb[i2], of[mf][i2], 0, 0, 0);
            }
            for (int i2 = 0; i2 < 2; i2++)
                lacc[i2] = __builtin_amdgcn_mfma_f32_16x16x32_bf16(
                    ones, pb[i2], lacc[i2], 0, 0, 0);
        }
        __syncthreads();
        if (jt < 15) {
            for (int e = 0; e < 2; e++) {
                gl_lds16(Ksrc + (size_t)(jt + 1) * 8192 + e * 1024, kb + e * 1024);
                gl_lds16(Vsrc + (size_t)(jt + 1) * 128 + (size_t)e * 32768, vb + e * 1024);
            }
        }
        __syncthreads();
    }
    float l0 = lacc[0][0], l1 = lacc[1][0];
    if (w >= 4) {
        float* ex = (float*)smem + (w - 4) * 2048;
        for (int mf = 0; mf < 4; mf++)
            for (int i2 = 0; i2 < 2; i2++)
                *(f32x4*)(ex + (mf * 2 + i2) * 256 + lane * 4) = of[mf][i2];
        if (lane < 16) { lxp[(w - 4) * 32 + lane] = l0; lxp[(w - 4) * 32 + 16 + lane] = l1; }
    }
    __syncthreads();
    if (w < 4) {
        float* ex = (float*)smem + w * 2048;
        for (int mf = 0; mf < 4; mf++)
            for (int i2 = 0; i2 < 2; i2++)
                of[mf][i2] += *(f32x4*)(ex + (mf * 2 + i2) * 256 + lane * 4);
        l0 += lxp[w * 32 + c];
        l1 += lxp[w * 32 + 16 + c];
        float inv0 = 1.f / l0, inv1 = 1.f / l1;
        for (int mf = 0; mf < 4; mf++) {
            *(uint2*)(plw + (0 * 16 + c) * 72 + mf * 16 + q * 4) =
                make_uint2(pack2(of[mf][0][0] * inv0, of[mf][0][1] * inv0),
                           pack2(of[mf][0][2] * inv0, of[mf][0][3] * inv0));
            *(uint2*)(plw + (1 * 16 + c) * 72 + mf * 16 + q * 4) =
                make_uint2(pack2(of[mf][1][0] * inv1, of[mf][1][1] * inv1),
                           pack2(of[mf][1][2] * inv1, of[mf][1][3] * inv1));
        }
        int b2 = bh >> 4, h = bh & 15;
        for (int e = 0; e < 4; e++) {
            int chn = e * 64 + lane;
            int i = chn >> 3, db = (chn & 7) * 16;
            float4 v = *(float4*)((char*)plw + i * 144 + db);
            int token = b2 * 2048 + qt * 128 + w * 32 + i;
            *(float4*)((char*)Ob + (size_t)token * 2048 + h * 128 + db) = v;
        }
    }
}

// ---------------- GEMM2 (r12-proven revert): plain stores, 512 blocks --
__global__ __launch_bounds__(256) void gemm_out(const short* __restrict__ A,
                                                const short* __restrict__ Bt,
                                                const float* __restrict__ bias,
                                                float* __restrict__ out) {
    __shared__ short As[2][128 * 32];
    __shared__ short Bs[2][64 * 32];
    int gid = blockIdx.x;
    int sg = gid >> 4, wi = gid & 15;
    int mt = (sg / 4) * 4 + (wi >> 2);
    int nt = (sg % 4) * 4 + (wi & 3);
    int t = threadIdx.x, w = t >> 6, lane = t & 63, c = lane & 15, q = lane >> 4;
    int mw = (w & 1) * 64, nw = (w >> 1) * 32;
    int h3 = lane >> 3, s3 = lane & 7, cp = s3 ^ h3;
    int rowin = 2 * h3 + (cp >> 2), koff = (cp & 3) * 16;
    const char* Ag0 = (const char*)A + (size_t)(mt * 128 + w * 32 + rowin) * 2048 + koff;
    const char* Ag1 = Ag0 + (size_t)16 * 2048;
    const char* Bg0 = (const char*)Bt + (size_t)(nt * 64 + w * 16 + rowin) * 2048 + koff;
    int cb = (c >> 1) * 128 + ((((c & 1) * 4 + q) ^ ((c >> 1) & 7)) * 16);
    f32x4 acc[4][2] = {};
    gl_lds16(Ag0, (char*)As[0] + w * 2048);
    gl_lds16(Ag1, (char*)As[0] + w * 2048 + 1024);
    gl_lds16(Bg0, (char*)Bs[0] + w * 1024);
    __syncthreads();
    for (int kt = 0; kt < 32; kt++) {
        int bu = kt & 1;
        if (kt < 31) {
            gl_lds16(Ag0 + (kt + 1) * 64, (char*)As[bu ^ 1] + w * 2048);
            gl_lds16(Ag1 + (kt + 1) * 64, (char*)As[bu ^ 1] + w * 2048 + 1024);
            gl_lds16(Bg0 + (kt + 1) * 64, (char*)Bs[bu ^ 1] + w * 1024);
        }
        bf16x8 af[4], bfr[2];
        for (int mf = 0; mf < 4; mf++)
            af[mf] = *(bf16x8*)((char*)As[bu] + (mw + mf * 16) * 64 + cb);
        for (int nf = 0; nf < 2; nf++)
            bfr[nf] = *(bf16x8*)((char*)Bs[bu] + (nw + nf * 16) * 64 + cb);
        for (int mf = 0; mf < 4; mf++)
            for (int nf = 0; nf < 2; nf++)
                acc[mf][nf] = __builtin_amdgcn_mfma_f32_16x16x32_bf16(
                    af[mf], bfr[nf], acc[mf][nf], 0, 0, 0);
        __syncthreads();
    }
    for (int nf = 0; nf < 2; nf++) {
        int col = nt * 64 + nw + nf * 16 + c;
        float bv = bias[col];
        for (int mf = 0; mf < 4; mf++) {
            int m0 = mt * 128 + mw + mf * 16 + q * 4;
            float* dst = out + (size_t)m0 * 1024 + col;
            dst[0]    = acc[mf][nf][0] + bv;
            dst[1024] = acc[mf][nf][1] + bv;
            dst[2048] = acc[mf][nf][2] + bv;
            dst[3072] = acc[mf][nf][3] + bv;
        }
    }
}

extern "C" void kernel_launch(void* const* d_in, const int* in_sizes, int n_in,
                              void* d_out, int out_size, void* d_ws, size_t ws_size,
                              hipStream_t stream) {
    (void)in_sizes; (void)n_in; (void)out_size; (void)ws_size;
    const float* x     = (const float*)d_in[0];
    const float* w_qkv = (const float*)d_in[1];
    const float* w_out = (const float*)d_in[2];
    const float* b_out = (const float*)d_in[3];
    float* out = (float*)d_out;

    short* xb    = (short*)d_ws;
    short* wqkvt = xb    + 4096 * 1024;
    short* woutt = wqkvt + 3072 * 1024;
    short* Qb    = woutt + 1024 * 1024;
    short* Kb    = Qb    + BH * SEQ * HD;
    short* Vtb   = Kb    + BH * SEQ * HD;
    short* Ob    = Vtb   + BH * HD * SEQ;

    hipLaunchKernelGGL(prep, dim3(3072), dim3(256), 0, stream, x, w_qkv, w_out, xb, wqkvt, woutt);
    hipLaunchKernelGGL(gemm_qkv, dim3(1536), dim3(256), 0, stream, xb, wqkvt, Qb, Kb, Vtb);
    hipLaunchKernelGGL(flash_attn, dim3(32, 16), dim3(512), 0, stream, Qb, Kb, Vtb, Ob);
    hipLaunchKernelGGL(gemm_out, dim3(512), dim3(256), 0, stream, Ob, woutt, b_out, out);
}

// Round 15
// 183.900 us; speedup vs baseline: 1.1378x; 1.0204x over previous
//
#include <hip/hip_runtime.h>
#include <stdint.h>

// Shapes (fixed by problem)
#define DIMD 1024
#define HEADS 16
#define HD 64
#define SEQ 2048
#define NBATCH 2
#define TOKENS 4096
#define BH 32

typedef __bf16 bf16x8 __attribute__((ext_vector_type(8)));
typedef float f32x4 __attribute__((ext_vector_type(4)));

#if __has_builtin(__builtin_amdgcn_exp2f)
#define EXP2(x) __builtin_amdgcn_exp2f(x)
#else
#define EXP2(x) exp2f(x)
#endif

#if __has_builtin(__builtin_amdgcn_cvt_pk_bf16_f32)
typedef __bf16 bf16x2 __attribute__((ext_vector_type(2)));
__device__ inline unsigned int pack2(float a, float b) {
    bf16x2 r = __builtin_amdgcn_cvt_pk_bf16_f32(a, b);
    return __builtin_bit_cast(unsigned int, r);
}
__device__ inline unsigned short f2bf(float f) {
    bf16x2 r = __builtin_amdgcn_cvt_pk_bf16_f32(f, f);
    return (unsigned short)(__builtin_bit_cast(unsigned int, r) & 0xffffu);
}
#else
__device__ inline unsigned short f2bf(float f) {
    unsigned int u = __builtin_bit_cast(unsigned int, f) + 0x8000u;
    return (unsigned short)(u >> 16);
}
__device__ inline unsigned int pack2(float a, float b) {
    unsigned int ua = __builtin_bit_cast(unsigned int, a) + 0x8000u;
    unsigned int ub = __builtin_bit_cast(unsigned int, b) + 0x8000u;
    return (ua >> 16) | (ub & 0xffff0000u);
}
#endif

// async global->LDS, 16B per lane, dest = wave-uniform base + lane*16
__device__ inline void gl_lds16(const void* g, void* l) {
    __builtin_amdgcn_global_load_lds(
        (const __attribute__((address_space(1))) unsigned int*)g,
        (__attribute__((address_space(3))) unsigned int*)l, 16, 0, 0);
}

// log2(e) * DIM^-0.5  (folded into Q at GEMM1 epilogue)
#define CEQ 0.0450842200277801f

// ------------- prep: cast x -> bf16 AND transpose-cast both weights ----
__global__ __launch_bounds__(256) void prep(const float* __restrict__ x,
                                            const float* __restrict__ wqkv,
                                            const float* __restrict__ wout,
                                            short* __restrict__ xb,
                                            short* __restrict__ wqkvt,
                                            short* __restrict__ woutt) {
    __shared__ short T[64 * 68];
    int bid = blockIdx.x, t = threadIdx.x;
    if (bid < 2048) {
        int g = bid * 256 + t;
        const float4* p = (const float4*)x + (size_t)g * 2;
        float4 a = p[0], b = p[1];
        uint4 o;
        o.x = pack2(a.x, a.y); o.y = pack2(a.z, a.w);
        o.z = pack2(b.x, b.y); o.w = pack2(b.z, b.w);
        ((uint4*)xb)[g] = o;
        return;
    }
    const float* w; short* wt; int N, n0, k0;
    if (bid < 2816) { int l = bid - 2048; w = wqkv; wt = wqkvt; N = 3072; n0 = (l % 48) * 64; k0 = (l / 48) * 64; }
    else            { int l = bid - 2816; w = wout; wt = woutt; N = 1024; n0 = (l % 16) * 64; k0 = (l / 16) * 64; }
    for (int e = 0; e < 4; e++) {
        int lin = t + e * 256;
        int r = lin >> 4, c = (lin & 15) * 4;
        float4 v = *(const float4*)(w + (size_t)(k0 + r) * N + n0 + c);
        *(uint2*)&T[r * 68 + c] = make_uint2(pack2(v.x, v.y), pack2(v.z, v.w));
    }
    __syncthreads();
    for (int e = 0; e < 4; e++) {
        int lin = t + e * 256;
        int nr = lin >> 4, kc = (lin & 15) * 4;
        unsigned short a0 = (unsigned short)T[(kc + 0) * 68 + nr];
        unsigned short a1 = (unsigned short)T[(kc + 1) * 68 + nr];
        unsigned short a2 = (unsigned short)T[(kc + 2) * 68 + nr];
        unsigned short a3 = (unsigned short)T[(kc + 3) * 68 + nr];
        *(uint2*)(wt + (size_t)(n0 + nr) * 1024 + k0 + kc) =
            make_uint2((unsigned int)a0 | ((unsigned int)a1 << 16),
                       (unsigned int)a2 | ((unsigned int)a3 << 16));
    }
}

// ---------------- GEMM1 (r10-proven): 128x128 dbuf single-barrier ------
__global__ __launch_bounds__(256) void gemm_qkv(const short* __restrict__ A,
                                                const short* __restrict__ Bt,
                                                short* __restrict__ Qb,
                                                short* __restrict__ Kb,
                                                short* __restrict__ Vtb) {
    __shared__ short As[2][128 * 32];
    __shared__ short Bs[2][128 * 32];
    int gid = blockIdx.x;
    int sg = gid >> 4, wi = gid & 15;
    int mt = (sg / 6) * 4 + (wi >> 2);
    int nt = (sg % 6) * 4 + (wi & 3);
    int t = threadIdx.x, w = t >> 6, lane = t & 63, c = lane & 15, q = lane >> 4;
    int mw = (w & 1) * 64, nw = (w >> 1) * 64;
    int h3 = lane >> 3, s3 = lane & 7, cp = s3 ^ h3;
    int rowin = 2 * h3 + (cp >> 2), koff = (cp & 3) * 16;
    const char* Ag0 = (const char*)A + (size_t)(mt * 128 + w * 32 + rowin) * 2048 + koff;
    const char* Ag1 = Ag0 + (size_t)16 * 2048;
    const char* Bg0 = (const char*)Bt + (size_t)(nt * 128 + w * 32 + rowin) * 2048 + koff;
    const char* Bg1 = Bg0 + (size_t)16 * 2048;
    int cb = (c >> 1) * 128 + ((((c & 1) * 4 + q) ^ ((c >> 1) & 7)) * 16);
    f32x4 acc[4][4] = {};
    gl_lds16(Ag0, (char*)As[0] + w * 2048);
    gl_lds16(Ag1, (char*)As[0] + w * 2048 + 1024);
    gl_lds16(Bg0, (char*)Bs[0] + w * 2048);
    gl_lds16(Bg1, (char*)Bs[0] + w * 2048 + 1024);
    __syncthreads();
    for (int kt = 0; kt < 32; kt++) {
        int bu = kt & 1;
        if (kt < 31) {
            gl_lds16(Ag0 + (kt + 1) * 64, (char*)As[bu ^ 1] + w * 2048);
            gl_lds16(Ag1 + (kt + 1) * 64, (char*)As[bu ^ 1] + w * 2048 + 1024);
            gl_lds16(Bg0 + (kt + 1) * 64, (char*)Bs[bu ^ 1] + w * 2048);
            gl_lds16(Bg1 + (kt + 1) * 64, (char*)Bs[bu ^ 1] + w * 2048 + 1024);
        }
        bf16x8 af[4], bfr[4];
        for (int mf = 0; mf < 4; mf++)
            af[mf] = *(bf16x8*)((char*)As[bu] + (mw + mf * 16) * 64 + cb);
        for (int nf = 0; nf < 4; nf++)
            bfr[nf] = *(bf16x8*)((char*)Bs[bu] + (nw + nf * 16) * 64 + cb);
        for (int mf = 0; mf < 4; mf++)
            for (int nf = 0; nf < 4; nf++)
                acc[mf][nf] = __builtin_amdgcn_mfma_f32_16x16x32_bf16(
                    af[mf], bfr[nf], acc[mf][nf], 0, 0, 0);
        __syncthreads();
    }
    for (int nf = 0; nf < 4; nf++) {
        int col = nt * 128 + nw + nf * 16 + c;
        int sel = col >> 10, cw = col & 1023, h = cw >> 6, d = cw & 63;
        float sc = (sel == 0) ? CEQ : 1.0f;
        for (int mf = 0; mf < 4; mf++) {
            int m0 = mt * 128 + mw + mf * 16 + q * 4;
            int b = m0 >> 11, nn = m0 & 2047;
            int bh = b * 16 + h;
            if (sel == 2) {
                *(uint2*)(Vtb + ((size_t)bh * 64 + d) * 2048 + nn) =
                    make_uint2(pack2(acc[mf][nf][0], acc[mf][nf][1]),
                               pack2(acc[mf][nf][2], acc[mf][nf][3]));
            } else {
                short* dst = (sel ? Kb : Qb) + ((size_t)bh * 2048 + nn) * 64 + d;
                dst[0]   = (short)f2bf(acc[mf][nf][0] * sc);
                dst[64]  = (short)f2bf(acc[mf][nf][1] * sc);
                dst[128] = (short)f2bf(acc[mf][nf][2] * sc);
                dst[192] = (short)f2bf(acc[mf][nf][3] * sc);
            }
        }
    }
}

// ---------------- flash attention v7 (r13/r14-proven): l via ones-MFMA -
__global__ __launch_bounds__(512, 4) void flash_attn(const short* __restrict__ Qb,
                                                     const short* __restrict__ Kb,
                                                     const short* __restrict__ Vtb,
                                                     short* __restrict__ Ob) {
    __shared__ __align__(16) char smem[70144];
    char* ktp = smem;
    char* vtp = smem + 16384;
    char* plp = smem + 32768;
    float* lxp = (float*)(smem + 69632);
    int bh = blockIdx.x, qt = blockIdx.y;
    int t = threadIdx.x, w = t >> 6, lane = t & 63, c = lane & 15, q = lane >> 4;
    int wi = w & 3, hf = w >> 2;
    const short* Qh = Qb + (size_t)bh * SEQ * HD;
    short* plw = (short*)(plp + w * 4608);
    bf16x8 bq[2][2];
    for (int i2 = 0; i2 < 2; i2++)
        for (int ks = 0; ks < 2; ks++)
            bq[i2][ks] = *(const bf16x8*)(Qh + (size_t)(qt * 128 + wi * 32 + i2 * 16 + c) * 64 + ks * 32 + q * 8);
    int rl = lane >> 3, sl = lane & 7, ch = sl ^ rl;
    const char* Ksrc = (const char*)(Kb + (size_t)bh * SEQ * HD)
                       + (size_t)(hf * 1024 + wi * 16 + rl) * 128 + ch * 16;
    const char* Vsrc = (const char*)(Vtb + (size_t)bh * HD * SEQ)
                       + (size_t)(wi * 16 + rl) * 4096 + hf * 2048 + ch * 16;
    char* kb = ktp + hf * 8192 + wi * 2048;
    char* vb = vtp + hf * 8192 + wi * 2048;
    char* kth = ktp + hf * 8192;
    char* vth = vtp + hf * 8192;
    int sw0 = ((0 * 4 + q) ^ (c & 7)) * 16;
    int sw1 = ((1 * 4 + q) ^ (c & 7)) * 16;
    bf16x8 ones;
    {
        unsigned short ob = 0x3F80;
        __bf16 ov = __builtin_bit_cast(__bf16, ob);
        for (int e = 0; e < 8; e++) ones[e] = ov;
    }
    f32x4 lacc[2] = {};
    f32x4 of[4][2] = {};
    for (int e = 0; e < 2; e++) {
        gl_lds16(Ksrc + e * 1024, kb + e * 1024);
        gl_lds16(Vsrc + (size_t)e * 32768, vb + e * 1024);
    }
    __syncthreads();
    for (int jt = 0; jt < 16; jt++) {
        f32x4 st[4][2] = {};
        for (int jf = 0; jf < 4; jf++) {
            bf16x8 ka0 = *(bf16x8*)(kth + (jf * 16 + c) * 128 + sw0);
            bf16x8 ka1 = *(bf16x8*)(kth + (jf * 16 + c) * 128 + sw1);
            for (int i2 = 0; i2 < 2; i2++)
                st[jf][i2] = __builtin_amdgcn_mfma_f32_16x16x32_bf16(
                    ka0, bq[i2][0], st[jf][i2], 0, 0, 0);
            for (int i2 = 0; i2 < 2; i2++)
                st[jf][i2] = __builtin_amdgcn_mfma_f32_16x16x32_bf16(
                    ka1, bq[i2][1], st[jf][i2], 0, 0, 0);
        }
        for (int i2 = 0; i2 < 2; i2++) {
            for (int jf = 0; jf < 4; jf++) {
                float p0 = EXP2(st[jf][i2][0]);
                float p1 = EXP2(st[jf][i2][1]);
                float p2 = EXP2(st[jf][i2][2]);
                float p3 = EXP2(st[jf][i2][3]);
                *(uint2*)(plw + (i2 * 16 + c) * 72 + jf * 16 + q * 4) =
                    make_uint2(pack2(p0, p1), pack2(p2, p3));
            }
        }
        for (int ks = 0; ks < 2; ks++) {
            int swk = ks ? sw1 : sw0;
            bf16x8 pb[2];
            for (int i2 = 0; i2 < 2; i2++)
                pb[i2] = *(bf16x8*)((char*)plw + (i2 * 16 + c) * 144 + ks * 64 + q * 16);
            for (int mf = 0; mf < 4; mf++) {
                bf16x8 va = *(bf16x8*)(vth + (mf * 16 + c) * 128 + swk);
                for (int i2 = 0; i2 < 2; i2++)
                    of[mf][i2] = __builtin_amdgcn_mfma_f32_16x16x32_bf16(
                        va, pb[i2], of[mf][i2], 0, 0, 0);
            }
            for (int i2 = 0; i2 < 2; i2++)
                lacc[i2] = __builtin_amdgcn_mfma_f32_16x16x32_bf16(
                    ones, pb[i2], lacc[i2], 0, 0, 0);
        }
        __syncthreads();
        if (jt < 15) {
            for (int e = 0; e < 2; e++) {
                gl_lds16(Ksrc + (size_t)(jt + 1) * 8192 + e * 1024, kb + e * 1024);
                gl_lds16(Vsrc + (size_t)(jt + 1) * 128 + (size_t)e * 32768, vb + e * 1024);
            }
        }
        __syncthreads();
    }
    float l0 = lacc[0][0], l1 = lacc[1][0];
    if (w >= 4) {
        float* ex = (float*)smem + (w - 4) * 2048;
        for (int mf = 0; mf < 4; mf++)
            for (int i2 = 0; i2 < 2; i2++)
                *(f32x4*)(ex + (mf * 2 + i2) * 256 + lane * 4) = of[mf][i2];
        if (lane < 16) { lxp[(w - 4) * 32 + lane] = l0; lxp[(w - 4) * 32 + 16 + lane] = l1; }
    }
    __syncthreads();
    if (w < 4) {
        float* ex = (float*)smem + w * 2048;
        for (int mf = 0; mf < 4; mf++)
            for (int i2 = 0; i2 < 2; i2++)
                of[mf][i2] += *(f32x4*)(ex + (mf * 2 + i2) * 256 + lane * 4);
        l0 += lxp[w * 32 + c];
        l1 += lxp[w * 32 + 16 + c];
        float inv0 = 1.f / l0, inv1 = 1.f / l1;
        for (int mf = 0; mf < 4; mf++) {
            *(uint2*)(plw + (0 * 16 + c) * 72 + mf * 16 + q * 4) =
                make_uint2(pack2(of[mf][0][0] * inv0, of[mf][0][1] * inv0),
                           pack2(of[mf][0][2] * inv0, of[mf][0][3] * inv0));
            *(uint2*)(plw + (1 * 16 + c) * 72 + mf * 16 + q * 4) =
                make_uint2(pack2(of[mf][1][0] * inv1, of[mf][1][1] * inv1),
                           pack2(of[mf][1][2] * inv1, of[mf][1][3] * inv1));
        }
        int b2 = bh >> 4, h = bh & 15;
        for (int e = 0; e < 4; e++) {
            int chn = e * 64 + lane;
            int i = chn >> 3, db = (chn & 7) * 16;
            float4 v = *(float4*)((char*)plw + i * 144 + db);
            int token = b2 * 2048 + qt * 128 + w * 32 + i;
            *(float4*)((char*)Ob + (size_t)token * 2048 + h * 128 + db) = v;
        }
    }
}

// ---------------- GEMM2 (r12-proven): plain stores, 512 blocks ---------
__global__ __launch_bounds__(256) void gemm_out(const short* __restrict__ A,
                                                const short* __restrict__ Bt,
                                                const float* __restrict__ bias,
                                                float* __restrict__ out) {
    __shared__ short As[2][128 * 32];
    __shared__ short Bs[2][64 * 32];
    int gid = blockIdx.x;
    int sg = gid >> 4, wi = gid & 15;
    int mt = (sg / 4) * 4 + (wi >> 2);
    int nt = (sg % 4) * 4 + (wi & 3);
    int t = threadIdx.x, w = t >> 6, lane = t & 63, c = lane & 15, q = lane >> 4;
    int mw = (w & 1) * 64, nw = (w >> 1) * 32;
    int h3 = lane >> 3, s3 = lane & 7, cp = s3 ^ h3;
    int rowin = 2 * h3 + (cp >> 2), koff = (cp & 3) * 16;
    const char* Ag0 = (const char*)A + (size_t)(mt * 128 + w * 32 + rowin) * 2048 + koff;
    const char* Ag1 = Ag0 + (size_t)16 * 2048;
    const char* Bg0 = (const char*)Bt + (size_t)(nt * 64 + w * 16 + rowin) * 2048 + koff;
    int cb = (c >> 1) * 128 + ((((c & 1) * 4 + q) ^ ((c >> 1) & 7)) * 16);
    f32x4 acc[4][2] = {};
    gl_lds16(Ag0, (char*)As[0] + w * 2048);
    gl_lds16(Ag1, (char*)As[0] + w * 2048 + 1024);
    gl_lds16(Bg0, (char*)Bs[0] + w * 1024);
    __syncthreads();
    for (int kt = 0; kt < 32; kt++) {
        int bu = kt & 1;
        if (kt < 31) {
            gl_lds16(Ag0 + (kt + 1) * 64, (char*)As[bu ^ 1] + w * 2048);
            gl_lds16(Ag1 + (kt + 1) * 64, (char*)As[bu ^ 1] + w * 2048 + 1024);
            gl_lds16(Bg0 + (kt + 1) * 64, (char*)Bs[bu ^ 1] + w * 1024);
        }
        bf16x8 af[4], bfr[2];
        for (int mf = 0; mf < 4; mf++)
            af[mf] = *(bf16x8*)((char*)As[bu] + (mw + mf * 16) * 64 + cb);
        for (int nf = 0; nf < 2; nf++)
            bfr[nf] = *(bf16x8*)((char*)Bs[bu] + (nw + nf * 16) * 64 + cb);
        for (int mf = 0; mf < 4; mf++)
            for (int nf = 0; nf < 2; nf++)
                acc[mf][nf] = __builtin_amdgcn_mfma_f32_16x16x32_bf16(
                    af[mf], bfr[nf], acc[mf][nf], 0, 0, 0);
        __syncthreads();
    }
    for (int nf = 0; nf < 2; nf++) {
        int col = nt * 64 + nw + nf * 16 + c;
        float bv = bias[col];
        for (int mf = 0; mf < 4; mf++) {
            int m0 = mt * 128 + mw + mf * 16 + q * 4;
            float* dst = out + (size_t)m0 * 1024 + col;
            dst[0]    = acc[mf][nf][0] + bv;
            dst[1024] = acc[mf][nf][1] + bv;
            dst[2048] = acc[mf][nf][2] + bv;
            dst[3072] = acc[mf][nf][3] + bv;
        }
    }
}

extern "C" void kernel_launch(void* const* d_in, const int* in_sizes, int n_in,
                              void* d_out, int out_size, void* d_ws, size_t ws_size,
                              hipStream_t stream) {
    (void)in_sizes; (void)n_in; (void)out_size; (void)ws_size;
    const float* x     = (const float*)d_in[0];
    const float* w_qkv = (const float*)d_in[1];
    const float* w_out = (const float*)d_in[2];
    const float* b_out = (const float*)d_in[3];
    float* out = (float*)d_out;

    short* xb    = (short*)d_ws;
    short* wqkvt = xb    + 4096 * 1024;
    short* woutt = wqkvt + 3072 * 1024;
    short* Qb    = woutt + 1024 * 1024;
    short* Kb    = Qb    + BH * SEQ * HD;
    short* Vtb   = Kb    + BH * SEQ * HD;
    short* Ob    = Vtb   + BH * HD * SEQ;

    hipLaunchKernelGGL(prep, dim3(3072), dim3(256), 0, stream, x, w_qkv, w_out, xb, wqkvt, woutt);
    hipLaunchKernelGGL(gemm_qkv, dim3(768), dim3(256), 0, stream, xb, wqkvt, Qb, Kb, Vtb);
    hipLaunchKernelGGL(flash_attn, dim3(32, 16), dim3(512), 0, stream, Qb, Kb, Vtb, Ob);
    hipLaunchKernelGGL(gemm_out, dim3(512), dim3(256), 0, stream, Ob, woutt, b_out, out);
}